// Round 9
// baseline (448.474 us; speedup 1.0000x reference)
//
#include <hip/hip_runtime.h>
#include <hip/hip_bf16.h>

namespace {

constexpr int B  = 2;
constexpr int S  = 2048;
constexpr int D  = 1024;
constexpr int H  = 16;
constexpr int BH = B * H;           // 32
constexpr float SCALE = 0.125f;     // HD^-0.5
constexpr float LOG2E = 1.44269504f;
constexpr float SL2   = SCALE * LOG2E;   // folded into Q at GEMM epilogue
constexpr float THR2  = 8.0f * LOG2E;    // defer-max threshold, log2 domain

constexpr int GM = B * S;   // 4096
constexpr int GN = D;       // 1024
constexpr int GK = D;       // 1024

typedef __bf16 bf16x8 __attribute__((ext_vector_type(8)));
typedef float  f32x4  __attribute__((ext_vector_type(4)));
typedef unsigned short u16;
typedef u16 u16x8 __attribute__((ext_vector_type(8)));
typedef u16 u16x4 __attribute__((ext_vector_type(4)));

__device__ __forceinline__ u16 f2bf(float f) {
  union { float f; unsigned u; } v{f};
  unsigned r = v.u + 0x7fffu + ((v.u >> 16) & 1u);   // RNE
  return (u16)(r >> 16);
}

__device__ __forceinline__ f32x4 mfma16(bf16x8 a, bf16x8 b, f32x4 c) {
  return __builtin_amdgcn_mfma_f32_16x16x32_bf16(a, b, c, 0, 0, 0);
}

__device__ __forceinline__ void gload_lds16(const u16* g, u16* l) {
  __builtin_amdgcn_global_load_lds(
      (const __attribute__((address_space(1))) void*)g,
      (__attribute__((address_space(3))) void*)l, 16, 0, 0);
}

// ---------------- fp32 -> bf16 conversion (batched over blockIdx.z) --------
__global__ __launch_bounds__(256) void cvt3_k(
    const float* __restrict__ a, const float* __restrict__ b,
    const float* __restrict__ c, u16* __restrict__ da,
    u16* __restrict__ db, u16* __restrict__ dc)
{
  const float* s = (blockIdx.z == 0) ? a : (blockIdx.z == 1) ? b : c;
  u16* d = (blockIdx.z == 0) ? da : (blockIdx.z == 1) ? db : dc;
  size_t i = ((size_t)blockIdx.x * 256 + threadIdx.x) * 4;
  float4 v = *(const float4*)&s[i];
  u16x4 o = { f2bf(v.x), f2bf(v.y), f2bf(v.z), f2bf(v.w) };
  *(u16x4*)&d[i] = o;
}

__global__ __launch_bounds__(256) void cvt4_k(
    const float* __restrict__ a, const float* __restrict__ b,
    const float* __restrict__ c, const float* __restrict__ e,
    u16* __restrict__ da, u16* __restrict__ db,
    u16* __restrict__ dc, u16* __restrict__ de)
{
  const float* s = (blockIdx.z == 0) ? a : (blockIdx.z == 1) ? b
                 : (blockIdx.z == 2) ? c : e;
  u16* d = (blockIdx.z == 0) ? da : (blockIdx.z == 1) ? db
         : (blockIdx.z == 2) ? dc : de;
  size_t i = ((size_t)blockIdx.x * 256 + threadIdx.x) * 4;
  float4 v = *(const float4*)&s[i];
  u16x4 o = { f2bf(v.x), f2bf(v.y), f2bf(v.z), f2bf(v.w) };
  *(u16x4*)&d[i] = o;
}

// ---------------- bf16 MFMA GEMM, BMxBN tile, BK=32, kg-major LDS ----------
// C[M,N] = A[M,K] @ W[N,K]^T + bias. 4 waves (2x2), wave = BM/2 x BN/2.
// LDS cell [kg 0..3][row][8 u16]: fragment ds_read_b128 per 16-lane group is
// 256B contiguous -> conflict-free. gload_lds dest linear (wave-uniform base
// + lane*16). BK=32 -> 16KB dbuf/array -> 32KB total -> 4-5 blocks/CU.
// QKV: z selects A/W/bias/C; z==0 (Q) output pre-scaled by SL2 (log2 domain).
template <int BM, int BN, bool QKV>
__global__ __launch_bounds__(256) void gemmT_k(
    const u16* __restrict__ A0, const u16* __restrict__ A1, const u16* __restrict__ A2,
    const u16* __restrict__ W0, const u16* __restrict__ W1, const u16* __restrict__ W2,
    const float* __restrict__ b0, const float* __restrict__ b1, const float* __restrict__ b2,
    u16* __restrict__ C0, u16* __restrict__ C1, u16* __restrict__ C2,
    float* __restrict__ Cf)
{
  __shared__ u16 Al[2][4 * BM * 8];
  __shared__ u16 Bl[2][4 * BN * 8];

  const int z = QKV ? blockIdx.z : 0;
  const u16* Ap = (z == 0) ? A0 : (z == 1) ? A1 : A2;
  const u16* Wp = (z == 0) ? W0 : (z == 1) ? W1 : W2;
  const float* bias = (z == 0) ? b0 : (z == 1) ? b1 : b2;
  u16* Cb = (z == 0) ? C0 : (z == 1) ? C1 : C2;

  const int tid  = threadIdx.x;
  const int lane = tid & 63;
  const int w    = tid >> 6;
  const int wr = w >> 1, wc = w & 1;
  const int lg = lane >> 4, ll = lane & 15;
  const int bm = blockIdx.y * BM, bn = blockIdx.x * BN;

  auto STAGE = [&](int buf, int k0) {
#pragma unroll
    for (int i = 0; i < (4 * BM) / 256; ++i) {
      const int c = i * 256 + tid;
      const int kg = c / BM, row = c % BM;
      gload_lds16(&Ap[(size_t)(bm + row) * GK + k0 + kg * 8], &Al[buf][c * 8]);
    }
#pragma unroll
    for (int i = 0; i < (4 * BN) / 256; ++i) {
      const int c = i * 256 + tid;
      const int kg = c / BN, row = c % BN;
      gload_lds16(&Wp[(size_t)(bn + row) * GK + k0 + kg * 8], &Bl[buf][c * 8]);
    }
  };

  constexpr int MI = BM / 32, NI = BN / 32;
  f32x4 acc[MI][NI] = {};

  STAGE(0, 0);
  __syncthreads();

  int cur = 0;
  constexpr int NT = GK / 32;   // 32
  for (int t = 0; t < NT; ++t) {
    if (t + 1 < NT) STAGE(cur ^ 1, (t + 1) * 32);
    bf16x8 af[MI], bfr[NI];
#pragma unroll
    for (int mi = 0; mi < MI; ++mi) {
      const int arow = wr * (BM / 2) + mi * 16 + ll;
      af[mi] = *(const bf16x8*)&Al[cur][(lg * BM + arow) * 8];
    }
#pragma unroll
    for (int ni = 0; ni < NI; ++ni) {
      const int brow = wc * (BN / 2) + ni * 16 + ll;
      bfr[ni] = *(const bf16x8*)&Bl[cur][(lg * BN + brow) * 8];
    }
    __builtin_amdgcn_s_setprio(1);
#pragma unroll
    for (int mi = 0; mi < MI; ++mi)
#pragma unroll
      for (int ni = 0; ni < NI; ++ni)
        acc[mi][ni] = mfma16(af[mi], bfr[ni], acc[mi][ni]);
    __builtin_amdgcn_s_setprio(0);
    __syncthreads();
    cur ^= 1;
  }

  const float sc = (QKV && z == 0) ? SL2 : 1.0f;
#pragma unroll
  for (int ni = 0; ni < NI; ++ni) {
    const int gcol = bn + wc * (BN / 2) + ni * 16 + ll;
    const float bv = bias[gcol];
#pragma unroll
    for (int mi = 0; mi < MI; ++mi) {
      const int grow = bm + wr * (BM / 2) + mi * 16 + lg * 4;
#pragma unroll
      for (int r = 0; r < 4; ++r) {
        float v = (acc[mi][ni][r] + bv) * sc;
        if (QKV) Cb[(size_t)(grow + r) * GN + gcol] = f2bf(v);
        else     Cf[(size_t)(grow + r) * GN + gcol] = v;
      }
    }
  }
}

// ---------------- V transpose: Vbf[b,s,h*64+d] -> Vt[(b*H+h)*64+d][s] ------
__global__ __launch_bounds__(256) void transpose_v_k(
    const u16* __restrict__ Vb, u16* __restrict__ Vt)
{
  __shared__ u16 T[64][72];
  const int tid = threadIdx.x;
  const int bh = blockIdx.y, b = bh >> 4, h = bh & 15;
  const int s0 = blockIdx.x * 64;
#pragma unroll
  for (int it = 0; it < 2; ++it) {
    int idx = tid + it * 256;
    int s = idx >> 3, dc = idx & 7;
    *(uint4*)&T[s][dc * 8] =
        *(const uint4*)&Vb[(size_t)(b * S + s0 + s) * D + h * 64 + dc * 8];
  }
  __syncthreads();
#pragma unroll
  for (int it = 0; it < 2; ++it) {
    int idx = tid + it * 256;
    int d = idx >> 3, sc = idx & 7;
    u16x8 o;
#pragma unroll
    for (int jj = 0; jj < 8; ++jj) o[jj] = T[sc * 8 + jj][d];
    *(u16x8*)&Vt[((size_t)bh * 64 + d) * S + s0 + sc * 8] = o;
  }
}

// ---------------- MFMA flash attention (non-split, log2 domain) ------------
// grid (S/64, BH), 4 waves x 16 q-rows, 32 kv-tiles of 64, K dbuf in LDS
// (kg-major conflict-free), bias pre-scaled by lam*LOG2E folded into MFMA
// C-operand (prefetched into bc during previous tile's PV), Q pre-scaled by
// SCALE*LOG2E at projection -> QK output is directly the log2-domain score.
// Shuffle-free defer-max (T13); setprio around MFMA clusters (T5).
__global__ __launch_bounds__(256) void attn_k(
    const u16* __restrict__ Qb, const u16* __restrict__ Kb,
    const u16* __restrict__ Vt, const float* __restrict__ biasS,
    const float* __restrict__ lamp, u16* __restrict__ Ob)
{
  __shared__ u16 Kl[2][8 * 64 * 8];    // 2 x 8 KB, kg-major [kg 0..7][row][8]
  __shared__ __bf16 Pl[4][16][72];     // per-wave P, row stride 144B

  const int tid  = threadIdx.x;
  const int lane = tid & 63;
  const int w    = tid >> 6;
  const int lg = lane >> 4, ll = lane & 15;
  const int bh = blockIdx.y, b = bh >> 4, h = bh & 15;
  const int qw = blockIdx.x * 64 + w * 16;
  const float lamL2 = lamp[0] * LOG2E;

  bf16x8 aQ[2];
  {
    const u16* qrow = &Qb[(size_t)(b * S + qw + ll) * D + h * 64];
    aQ[0] = *(const bf16x8*)&qrow[lg * 8];
    aQ[1] = *(const bf16x8*)&qrow[32 + lg * 8];
  }

  const u16* Kbase = &Kb[(size_t)(b * S) * D + h * 64];
  const u16* Vbase = &Vt[(size_t)bh * 64 * S];
  const float* Bb  = &biasS[((size_t)b * S + qw + lg * 4) * S];

  auto STAGE_K = [&](int buf, int k0) {
#pragma unroll
    for (int i = 0; i < 2; ++i) {
      const int c = i * 256 + tid;           // 512 cells: [kg 0..7][row 0..63]
      const int kg = c >> 6, row = c & 63;
      gload_lds16(&Kbase[(size_t)(k0 + row) * D + kg * 8], &Kl[buf][c * 8]);
    }
  };

  f32x4 accO[4] = {};
  float m_r[4], l_r[4];
#pragma unroll
  for (int r = 0; r < 4; ++r) { m_r[r] = -1e30f; l_r[r] = 0.f; }

  float bc[4][4];
  STAGE_K(0, 0);
#pragma unroll
  for (int r = 0; r < 4; ++r)
#pragma unroll
    for (int kf = 0; kf < 4; ++kf)
      bc[r][kf] = lamL2 * Bb[(size_t)r * S + kf * 16 + ll];
  __syncthreads();                     // buf0 staged

  int cur = 0;
  constexpr int NT = S / 64;           // 32
  for (int t = 0; t < NT; ++t) {
    const int k0 = t * 64;
    if (t + 1 < NT) STAGE_K(cur ^ 1, k0 + 64);

    // ---- QK^T from LDS; bias (pre-scaled) in the C-operand ----
    f32x4 sf[4];
#pragma unroll
    for (int kf = 0; kf < 4; ++kf) {
      bf16x8 kb0 = *(const bf16x8*)&Kl[cur][(lg * 64 + kf * 16 + ll) * 8];
      bf16x8 kb1 = *(const bf16x8*)&Kl[cur][((4 + lg) * 64 + kf * 16 + ll) * 8];
      f32x4 t4 = { bc[0][kf], bc[1][kf], bc[2][kf], bc[3][kf] };
      __builtin_amdgcn_s_setprio(1);
      t4 = mfma16(aQ[0], kb0, t4);
      t4 = mfma16(aQ[1], kb1, t4);
      __builtin_amdgcn_s_setprio(0);
      sf[kf] = t4;                     // already log2-domain score
    }

    // ---- bias prefetch for next tile (latency hidden under softmax+PV) ----
    if (t + 1 < NT) {
#pragma unroll
      for (int r = 0; r < 4; ++r)
#pragma unroll
        for (int kf = 0; kf < 4; ++kf)
          bc[r][kf] = lamL2 * Bb[(size_t)r * S + k0 + 64 + kf * 16 + ll];
    }

    // ---- defer-max online softmax (shuffle-free fast path) ----
    float pm[4];
#pragma unroll
    for (int r = 0; r < 4; ++r)
      pm[r] = fmaxf(fmaxf(sf[0][r], sf[1][r]), fmaxf(sf[2][r], sf[3][r]));
    float ex = fmaxf(fmaxf(pm[0] - m_r[0], pm[1] - m_r[1]),
                     fmaxf(pm[2] - m_r[2], pm[3] - m_r[3]));
    if (__any(ex > THR2)) {            // tile 0 always; rare after
#pragma unroll
      for (int r = 0; r < 4; ++r) {
        float tmx = pm[r];
        tmx = fmaxf(tmx, __shfl_xor(tmx, 1));
        tmx = fmaxf(tmx, __shfl_xor(tmx, 2));
        tmx = fmaxf(tmx, __shfl_xor(tmx, 4));
        tmx = fmaxf(tmx, __shfl_xor(tmx, 8));
        float nm = fmaxf(m_r[r], tmx);
        float cf = exp2f(m_r[r] - nm);
        m_r[r] = nm;
        l_r[r] *= cf;
#pragma unroll
        for (int nf = 0; nf < 4; ++nf) accO[nf][r] *= cf;
      }
    }
#pragma unroll
    for (int r = 0; r < 4; ++r) {
      float ps = 0.f;
#pragma unroll
      for (int kf = 0; kf < 4; ++kf) {
        float p = exp2f(sf[kf][r] - m_r[r]);
        Pl[w][lg * 4 + r][kf * 16 + ll] = (__bf16)p;
        ps += p;
      }
      l_r[r] += ps;                    // per-lane partial l
    }

    // ---- PV: V fragments transient per-nf ----
    bf16x8 aP0 = *(const bf16x8*)&Pl[w][ll][lg * 8];
    bf16x8 aP1 = *(const bf16x8*)&Pl[w][ll][32 + lg * 8];
#pragma unroll
    for (int nf = 0; nf < 4; ++nf) {
      const u16* vrow = &Vbase[(size_t)(nf * 16 + ll) * S + k0];
      bf16x8 v0 = *(const bf16x8*)&vrow[lg * 8];
      bf16x8 v1 = *(const bf16x8*)&vrow[32 + lg * 8];
      __builtin_amdgcn_s_setprio(1);
      accO[nf] = mfma16(aP0, v0, accO[nf]);
      accO[nf] = mfma16(aP1, v1, accO[nf]);
      __builtin_amdgcn_s_setprio(0);
    }

    __syncthreads();                   // next K buffer staged; Kl reads done
    cur ^= 1;
  }

  // reduce per-lane partial l across the 16-lane row groups (once)
  float inv[4];
#pragma unroll
  for (int r = 0; r < 4; ++r) {
    float tl = l_r[r];
    tl += __shfl_xor(tl, 1);
    tl += __shfl_xor(tl, 2);
    tl += __shfl_xor(tl, 4);
    tl += __shfl_xor(tl, 8);
    inv[r] = 1.0f / tl;
  }
#pragma unroll
  for (int nf = 0; nf < 4; ++nf)
#pragma unroll
    for (int r = 0; r < 4; ++r)
      Ob[(size_t)(b * S + qw + lg * 4 + r) * D + h * 64 + nf * 16 + ll] =
          f2bf(accO[nf][r] * inv[r]);
}

}  // namespace

extern "C" void kernel_launch(void* const* d_in, const int* in_sizes, int n_in,
                              void* d_out, int out_size, void* d_ws, size_t ws_size,
                              hipStream_t stream)
{
  const float* query = (const float*)d_in[0];
  const float* key   = (const float*)d_in[1];
  const float* value = (const float*)d_in[2];
  const float* biasS = (const float*)d_in[3];
  const float* Wq = (const float*)d_in[4];
  const float* bq = (const float*)d_in[5];
  const float* Wk = (const float*)d_in[6];
  const float* bk = (const float*)d_in[7];
  const float* Wv = (const float*)d_in[8];
  const float* bv = (const float*)d_in[9];
  const float* Wo = (const float*)d_in[10];
  const float* bo = (const float*)d_in[11];
  const float* lam = (const float*)d_in[12];
  float* out = (float*)d_out;

  // ws layout (48 MB):
  //  [0:8]   Xq  -> Obf (attn out; Xq dead after QKV GEMM)
  //  [8:16]  Xk, [16:24] Xv
  //  [24:32] WqB, WkB, WvB, WoB (2 MB each)
  //  [32:40] Qbf, [40:48] Kbf
  // d_out: [0:8MB] Vbf (until transpose), [8:16MB] Vt (until O-GEMM);
  //        final O-GEMM overwrites d_out entirely.
  char* ws = (char*)d_ws;
  const size_t MB = 1024 * 1024;
  u16* Xq  = (u16*)(ws + 0 * MB);
  u16* Xk  = (u16*)(ws + 8 * MB);
  u16* Xv  = (u16*)(ws + 16 * MB);
  u16* WqB = (u16*)(ws + 24 * MB);
  u16* WkB = (u16*)(ws + 26 * MB);
  u16* WvB = (u16*)(ws + 28 * MB);
  u16* WoB = (u16*)(ws + 30 * MB);
  u16* Qbf = (u16*)(ws + 32 * MB);
  u16* Kbf = (u16*)(ws + 40 * MB);
  u16* Obf = Xq;                               // 8 MB (over Xq)
  u16* Vbf = (u16*)d_out;                      // 8 MB
  u16* Vt  = (u16*)d_out + (size_t)4 * MB;     // 8 MB (4M u16 elems offset)

  // 1) fp32 -> bf16
  cvt3_k<<<dim3(4096, 1, 3), 256, 0, stream>>>(query, key, value, Xq, Xk, Xv);
  cvt4_k<<<dim3(1024, 1, 4), 256, 0, stream>>>(Wq, Wk, Wv, Wo, WqB, WkB, WvB, WoB);

  // 2) fused QKV projections: 128x128 tile, BK=32, z=3 -> 768 blocks
  dim3 pgrid(GN / 128, GM / 128, 3);           // (8, 32, 3)
  gemmT_k<128, 128, true><<<pgrid, 256, 0, stream>>>(
      Xq, Xk, Xv, WqB, WkB, WvB, bq, bk, bv, Qbf, Kbf, Vbf, nullptr);

  // 3) V transpose
  transpose_v_k<<<dim3(S / 64, BH), 256, 0, stream>>>(Vbf, Vt);

  // 4) flash attention (1024 blocks)
  attn_k<<<dim3(S / 64, BH), 256, 0, stream>>>(Qbf, Kbf, Vt, biasS, lam, Obf);

  // 5) output projection: 64x128 tile -> 512 blocks, fp32 out
  dim3 ogrid(GN / 128, GM / 64, 1);            // (8, 64)
  gemmT_k<64, 128, false><<<ogrid, 256, 0, stream>>>(
      Obf, nullptr, nullptr, WoB, nullptr, nullptr, bo, nullptr, nullptr,
      nullptr, nullptr, nullptr, out);
}